// Round 12
// baseline (216.782 us; speedup 1.0000x reference)
//
#include <hip/hip_runtime.h>
#include <math.h>

#define N_ 8192
#define D_ 512
#define NC_ 128
#define T_ 64      // 8192/128 row-tiles
#define BK_ 32     // K-step
#define KT_ 16     // 512/32 K-tiles
#define NCHUNK 544 // sum over it of ceil((64-it)/4)

typedef __attribute__((ext_vector_type(8))) short bf16x8;
typedef __attribute__((ext_vector_type(4))) float f32x4;
typedef __attribute__((ext_vector_type(4))) unsigned short us4;

static __device__ __forceinline__ unsigned short f2bf(float f) {
    union { float f; unsigned u; } c; c.f = f;
    unsigned u = c.u;
    u += 0x7fffu + ((u >> 16) & 1u);   // round-to-nearest-even
    return (unsigned short)(u >> 16);
}

// ---------- kernel 1: convert + last-row fp64 dots + histogram (wide) --------
__global__ __launch_bounds__(256) void k_pre(const float* __restrict__ x,
                                             unsigned short* __restrict__ xb,
                                             const int* __restrict__ tg,
                                             double* __restrict__ sim_last,
                                             int* __restrict__ hist32,
                                             double* __restrict__ gd,
                                             int* __restrict__ gi) {
    const int bid = blockIdx.x;
    const int tid = threadIdx.x;
    if (bid == 0 && tid == 0) {
        atomicExch((unsigned long long*)&gd[0], 0ull);
        atomicExch((unsigned long long*)&gd[1], 0ull);
        atomicExch((unsigned long long*)&gd[2], 0ull);
        atomicExch(&gi[0], 0); atomicExch(&gi[1], 0);
        atomicExch(&gi[2], 0); atomicExch(&gi[3], 0);
        atomicExch(&gi[4], 256);          // work-steal counter (chunks 256..543)
    }
    if (bid < 4096) {
        int i = bid * 256 + tid;
        float4 v = reinterpret_cast<const float4*>(x)[i];
        us4 o = { f2bf(v.x), f2bf(v.y), f2bf(v.z), f2bf(v.w) };
        reinterpret_cast<us4*>(xb)[i] = o;
    } else if (bid < 6144) {
        int j    = (bid - 4096) * 4 + (tid >> 6);
        int lane = tid & 63;
        const float* xl = x + (size_t)(N_ - 1) * D_;
        const float* xj = x + (size_t)j * D_;
        double acc = 0.0;
#pragma unroll
        for (int it = 0; it < 8; ++it) {
            int k = it * 64 + lane;
            acc += (double)xl[k] * (double)xj[k];
        }
#pragma unroll
        for (int m = 32; m >= 1; m >>= 1) acc += __shfl_xor(acc, m, 64);
        if (lane == 0) sim_last[j] = acc;
    } else {
        __shared__ int lh[NC_];
        int b = bid - 6144;                 // 0..31
        if (tid < NC_) lh[tid] = 0;
        __syncthreads();
        atomicAdd(&lh[tg[b * 256 + tid]], 1);
        __syncthreads();
        if (tid < NC_) hist32[b * NC_ + tid] = lh[tid];
    }
}

// ---------- kernel 2: A-panel-resident persistent MFMA (256 blocks, 1/CU) ----
// LDS 151 KB: A panel [16 kt][128 r][32 k] = 128 KB resident per chunk;
// B double-buffered 2x8 KB streamed with R11's exact counted-vmcnt TILE
// cadence (vmcnt(2), 2 barriers/tile); dedicated 4 KB scr for the epilogue.
// Work: 544 chunks (fixed it, up to 4 consecutive jt jobs). First 256 chunks
// static (= blockIdx), rest via atomic work-stealing (dynamic balance).
// Per job staged bytes: 128 KB (B only) vs R11's 256 KB; A reads are pure LDS.
// Job boundaries never drain: next-job B0/B1 staged during tiles 14/15.
__global__ __launch_bounds__(256, 1) void k_main(const unsigned short* __restrict__ xb,
                                                 const int* __restrict__ tg,
                                                 float* __restrict__ bufP,
                                                 float* __restrict__ bufN,
                                                 int* __restrict__ gi) {
    __shared__ alignas(16) unsigned short A_lds[KT_][128 * BK_];  // 128 KiB
    __shared__ alignas(16) unsigned short Bs[2][128 * BK_];       // 16 KiB
    __shared__ float scr[1024];                                   // 4 KiB
    __shared__ int sh_next;

    const int tid  = threadIdx.x;
    const int w    = tid >> 6;
    const int lane = tid & 63;
    const int q    = lane >> 4;
    const int l15  = lane & 15;
    const int wrow = w >> 1;      // 0..1
    const int wcol = w & 1;       // 0..1

    // stage one 8 KB K-tile (2 gload_lds/thread), R11's XOR-swizzled source:
    // LDS slot sl (of 4/row) holds kgroup g = sl ^ ((r>>1)&3).
    auto stage_arr = [&](unsigned short* dst, const unsigned short* src_base,
                         int r0, int k0) {
#pragma unroll
        for (int itr = 0; itr < 2; ++itr) {
            int slot = itr * 4 + w;          // 0..7
            int gs = slot * 64 + lane;       // 16B-chunk id 0..511
            int r  = gs >> 2;                // row 0..127
            int sl = gs & 3;
            int g  = sl ^ ((r >> 1) & 3);
            const unsigned short* ga = src_base + (size_t)(r0 + r) * D_ + k0 + g * 8;
            __builtin_amdgcn_global_load_lds(
                (const __attribute__((address_space(1))) void*)ga,
                (__attribute__((address_space(3))) void*)(dst + slot * 512),
                16, 0, 0);
        }
    };

    f32x4 acc[4][4];

    // one K-tile: 8 ds_read_b128 -> 16 MFMA (R11 verbatim; A from resident panel)
    auto compute_tile = [&](int kt) {
        const unsigned short* A = &A_lds[kt][0];
        const unsigned short* B = &Bs[kt & 1][0];
        bf16x8 aF[4], bF[4];
#pragma unroll
        for (int mi = 0; mi < 4; ++mi) {
            int rA = wrow * 64 + mi * 16 + l15;
            int sl = q ^ ((rA >> 1) & 3);
            aF[mi] = *reinterpret_cast<const bf16x8*>(A + rA * BK_ + sl * 8);
        }
#pragma unroll
        for (int ni = 0; ni < 4; ++ni) {
            int rB = wcol * 64 + ni * 16 + l15;
            int sl = q ^ ((rB >> 1) & 3);
            bF[ni] = *reinterpret_cast<const bf16x8*>(B + rB * BK_ + sl * 8);
        }
        asm volatile("s_waitcnt lgkmcnt(0)" ::: "memory");
        __builtin_amdgcn_sched_barrier(0);   // rule 18: MFMA must not hoist
        __builtin_amdgcn_s_setprio(1);
#pragma unroll
        for (int mi = 0; mi < 4; ++mi)
#pragma unroll
            for (int ni = 0; ni < 4; ++ni)
                acc[mi][ni] = __builtin_amdgcn_mfma_f32_16x16x32_bf16(
                    aF[mi], bF[ni], acc[mi][ni], 0, 0, 0);
        __builtin_amdgcn_s_setprio(0);
    };

    int id = blockIdx.x;                     // first chunk: static
    while (id < NCHUNK) {
        // decode chunk id -> (it, jt0, len): row it has ceil((64-it)/4) chunks
        int rem = id, it = 0;
        while (rem >= ((T_ - it + 3) >> 2)) { rem -= (T_ - it + 3) >> 2; it++; }
        const int jt0 = it + rem * 4;
        const int len = min(4, T_ - it - rem * 4);
        const int row0 = it * 128;

        // chunk prologue: full A panel (16 kt) + B tiles 0,1 of job 0.
        // WAR-safe: prior chunk's last reads sealed by its tile-15 trailing
        // barrier + chunk-claim __syncthreads.
#pragma unroll 1
        for (int kt = 0; kt < KT_; ++kt)
            stage_arr(&A_lds[kt][0], xb, row0, kt * BK_);
        stage_arr(&Bs[0][0], xb, jt0 * 128, 0);
        stage_arr(&Bs[1][0], xb, jt0 * 128, BK_);

#pragma unroll 1
        for (int j = 0; j < len; ++j) {
            const int jt   = jt0 + j;
            const int col0 = jt * 128;
            const bool has_next = (j < len - 1);

#pragma unroll
            for (int mi = 0; mi < 4; ++mi)
#pragma unroll
                for (int ni = 0; ni < 4; ++ni)
                    acc[mi][ni] = (f32x4){0.f, 0.f, 0.f, 0.f};

            // 16-tile K-loop, counted vmcnt(2): waits only the B stage issued
            // two tiles ago (A is resident). Stages at 14/15 feed the NEXT job
            // so the pipeline never drains inside a chunk.
#pragma unroll 1
            for (int kt = 0; kt < KT_; ++kt) {
                asm volatile("s_waitcnt vmcnt(2)" ::: "memory");
                __builtin_amdgcn_s_barrier();
                __builtin_amdgcn_sched_barrier(0);
                compute_tile(kt);
                __builtin_amdgcn_s_barrier();
                __builtin_amdgcn_sched_barrier(0);
                if (kt < KT_ - 2) {
                    stage_arr(&Bs[kt & 1][0], xb, col0, (kt + 2) * BK_);
                } else if (has_next) {
                    // kt==14 -> next job's tile 0 (buf 0); kt==15 -> tile 1 (buf 1)
                    stage_arr(&Bs[kt & 1][0], xb, col0 + 128, (kt & 1) * BK_);
                }
            }

            // ------------- epilogue (R11 verbatim; dedicated scr) -------------
            int tC[4];
#pragma unroll
            for (int ni = 0; ni < 4; ++ni)
                tC[ni] = tg[col0 + wcol * 64 + ni * 16 + l15];

            float ps[4][4], ns[4][4];
            float cps[4], cns[4];
            int tR[4][4];
#pragma unroll
            for (int mi = 0; mi < 4; ++mi)
#pragma unroll
                for (int r = 0; r < 4; ++r) {
                    ps[mi][r] = 0.f; ns[mi][r] = 0.f;
                    tR[mi][r] = tg[row0 + wrow * 64 + mi * 16 + q * 4 + r];
                }
#pragma unroll
            for (int ni = 0; ni < 4; ++ni) { cps[ni] = 0.f; cns[ni] = 0.f; }

#pragma unroll
            for (int mi = 0; mi < 4; ++mi)
#pragma unroll
                for (int ni = 0; ni < 4; ++ni)
#pragma unroll
                    for (int r = 0; r < 4; ++r) {
                        float s = acc[mi][ni][r];
                        bool same = (tR[mi][r] == tC[ni]);
                        float e = __expf(same ? 1.0f - s : s);
                        float pe = (same && (s < 1.0f)) ? e : 0.0f;
                        float ne = same ? 0.0f : e;
                        ps[mi][r] += pe; ns[mi][r] += ne;
                        cps[ni]   += pe; cns[ni]   += ne;
                    }

#pragma unroll
            for (int mi = 0; mi < 4; ++mi)
#pragma unroll
                for (int r = 0; r < 4; ++r) {
                    float p = ps[mi][r];
                    float n = ns[mi][r];
#pragma unroll
                    for (int m = 1; m < 16; m <<= 1) {
                        p += __shfl_xor(p, m, 64);
                        n += __shfl_xor(n, m, 64);
                    }
                    if (l15 == 0) {
                        int rloc = wrow * 64 + mi * 16 + q * 4 + r;
                        scr[wcol * 128 + rloc]       = p;
                        scr[256 + wcol * 128 + rloc] = n;
                    }
                }

#pragma unroll
            for (int ni = 0; ni < 4; ++ni) {
                float p = cps[ni];
                float n = cns[ni];
                p += __shfl_xor(p, 16, 64); p += __shfl_xor(p, 32, 64);
                n += __shfl_xor(n, 16, 64); n += __shfl_xor(n, 32, 64);
                if (q == 0) {
                    int cloc = wcol * 64 + ni * 16 + l15;
                    scr[512 + wrow * 128 + cloc] = p;
                    scr[768 + wrow * 128 + cloc] = n;
                }
            }
            __syncthreads();

            if (tid < 128) {
                int r = tid;
                size_t off = ((size_t)it * T_ + jt) * 128 + r;
                bufP[off] = scr[r]       + scr[128 + r];
                bufN[off] = scr[256 + r] + scr[384 + r];
            } else if (jt != it) {
                int c = tid - 128;
                size_t off = ((size_t)jt * T_ + it) * 128 + c;
                bufP[off] = scr[512 + c] + scr[640 + c];
                bufN[off] = scr[768 + c] + scr[896 + c];
            }
            __syncthreads();   // scr reads done before next job's epilogue rewrites
        }

        // claim next chunk (uniform broadcast; syncthreads drains stores)
        if (tid == 0) sh_next = atomicAdd(&gi[4], 1);
        __syncthreads();
        id = sh_next;
    }
}

// ---------- kernel 3: reduce + finalize (64 blocks, atomic-chained) ----------
__global__ __launch_bounds__(256) void k_post(const float* __restrict__ bufP,
                                              const float* __restrict__ bufN,
                                              const int* __restrict__ tg,
                                              const int* __restrict__ hist32,
                                              const double* __restrict__ sim_last,
                                              double* __restrict__ gd,
                                              int* __restrict__ gi,
                                              float* __restrict__ out) {
    __shared__ int lh[NC_];
    __shared__ float sv[256];
    __shared__ double Rd[256], Pd[256], Nd[256];
    __shared__ int Ri[256], Pc[256], Nc[256];
    const int t   = blockIdx.x;       // 0..63
    const int tid = threadIdx.x;

    if (tid < NC_) {
        int a = 0;
#pragma unroll
        for (int b = 0; b < 32; ++b) a += hist32[b * NC_ + tid];
        lh[tid] = a;
    }

    const int half = tid >> 7;        // 0: psum, 1: nsum
    const int r    = tid & 127;
    const float* buf  = half ? bufN : bufP;
    const float* base = buf + (size_t)t * T_ * 128 + r;
    float s = 0.f;
#pragma unroll
    for (int o = 0; o < T_; ++o) s += base[o * 128];
    sv[tid] = s;
    __syncthreads();

    double rd = 0.0, pd = 0.0, nd = 0.0;
    int ri = 0, pc = 0, nc = 0;
    if (tid < 128) {
        int row = t * 128 + tid;
        bool ok = lh[tg[row]] < N_;
        rd = ok ? (double)(logf(sv[tid]) + logf(sv[128 + tid])) : 0.0;
        ri = ok ? 0 : 1;
        double sl = sim_last[row];
        int tlast = tg[N_ - 1];
        if (tg[row] == tlast) { if (sl < 1.0) { pd = sl; pc = 1; } }
        else                  { nd = sl; nc = 1; }
    }

    Rd[tid] = rd; Ri[tid] = ri;
    Pd[tid] = pd; Pc[tid] = pc;
    Nd[tid] = nd; Nc[tid] = nc;
    __syncthreads();
    for (int st = 128; st >= 1; st >>= 1) {
        if (tid < st) {
            Rd[tid] += Rd[tid + st]; Pd[tid] += Pd[tid + st]; Nd[tid] += Nd[tid + st];
            Ri[tid] += Ri[tid + st]; Pc[tid] += Pc[tid + st]; Nc[tid] += Nc[tid + st];
        }
        __syncthreads();
    }

    if (tid == 0) {
        atomicAdd(&gd[0], Rd[0]);
        atomicAdd(&gd[1], Pd[0]);
        atomicAdd(&gd[2], Nd[0]);
        atomicAdd(&gi[0], Ri[0]);
        atomicAdd(&gi[1], Pc[0]);
        atomicAdd(&gi[2], Nc[0]);
        __threadfence();
        int old = atomicAdd(&gi[3], 1);
        if (old == 63) {
            double A = atomicAdd(&gd[0], 0.0);
            double B = atomicAdd(&gd[1], 0.0);
            double C = atomicAdd(&gd[2], 0.0);
            int U = atomicAdd(&gi[0], 0);
            int V = atomicAdd(&gi[1], 0);
            int Y = atomicAdd(&gi[2], 0);
            out[0] = (float)(A / (double)N_);
            out[1] = (float)U / (float)N_;
            out[2] = (float)(B / (double)V);
            out[3] = (float)(C / (double)Y);
        }
    }
}

extern "C" void kernel_launch(void* const* d_in, const int* in_sizes, int n_in,
                              void* d_out, int out_size, void* d_ws, size_t ws_size,
                              hipStream_t stream) {
    const float* x  = (const float*)d_in[0];
    const int*   tg = (const int*)d_in[1];
    char* ws = (char*)d_ws;

    unsigned short* xb = (unsigned short*)ws;                 // 8 MB
    const size_t XB = (size_t)N_ * D_ * 2;                    // 8388608
    float*  bufP = (float*)(ws + XB);                         // 2 MB
    float*  bufN = (float*)(ws + XB + 2097152);               // 2 MB
    double* sim_last = (double*)(ws + XB + 4194304);          // 64 KB
    int*    hist32   = (int*)(ws + XB + 4194304 + 65536);     // 16 KB
    double* gd   = (double*)(ws + XB + 4194304 + 65536 + 16384);      // 3 doubles
    int*    gi   = (int*)(ws + XB + 4194304 + 65536 + 16384 + 64);    // 8 ints

    hipLaunchKernelGGL(k_pre, dim3(4096 + 2048 + 32), dim3(256), 0, stream,
                       x, xb, tg, sim_last, hist32, gd, gi);
    hipLaunchKernelGGL(k_main, dim3(256), dim3(256), 0, stream,
                       xb, tg, bufP, bufN, gi);
    hipLaunchKernelGGL(k_post, dim3(64), dim3(256), 0, stream,
                       bufP, bufN, tg, hist32, sim_last, gd, gi, (float*)d_out);
}